// Round 4
// baseline (330.586 us; speedup 1.0000x reference)
//
#include <hip/hip_runtime.h>
#include <stdint.h>

// B=2, T=2048, D_MODEL=1536, H=16, hd=96, n_trip=32. qkv row = 4608, rows = 4096.

typedef unsigned short u16;
typedef unsigned int u32;
typedef __attribute__((ext_vector_type(8))) __bf16 bf16x8;   // MFMA A/B frag
typedef __attribute__((ext_vector_type(4))) float f32x4;     // MFMA C/D frag

#define DEV static __device__ __forceinline__

DEV u16 f2bf(float f) {
  u32 u = __float_as_uint(f);
  return (u16)((u + 0x7fffu + ((u >> 16) & 1u)) >> 16);  // RNE
}
DEV float bf2f(u16 h) { return __uint_as_float(((u32)h) << 16); }
DEV u32 cvtpk(float lo, float hi) {  // packed f32->bf16 pair (lo->bits[15:0])
  u32 r;
  asm("v_cvt_pk_bf16_f32 %0, %1, %2" : "=v"(r) : "v"(lo), "v"(hi));
  return r;
}
DEV float exp2f_fast(float x) {
  float r;
  asm("v_exp_f32 %0, %1" : "=v"(r) : "v"(x));
  return r;
}

// async global->LDS, 16B/lane. LDS dest = wave-uniform base + lane*16.
DEV void gload16(u16* lds_dst, const u16* gsrc) {
  __builtin_amdgcn_global_load_lds(
      (const __attribute__((address_space(1))) void*)gsrc,
      (__attribute__((address_space(3))) void*)lds_dst, 16, 0, 0);
}

// ---------------------------------------------------------------- cvt f32->bf16
__global__ __launch_bounds__(256) void cvt_bf16(const float* __restrict__ in,
                                                u16* __restrict__ out, int n4) {
  int i = blockIdx.x * 256 + threadIdx.x;
  if (i < n4) {
    float4 v = reinterpret_cast<const float4*>(in)[i];
    ushort4 o;
    o.x = f2bf(v.x); o.y = f2bf(v.y); o.z = f2bf(v.z); o.w = f2bf(v.w);
    reinterpret_cast<ushort4*>(out)[i] = o;
  }
}

// ---------------------------------------------------------------- GEMM (128²,2ph)
// kept for gemm2 (N=1536: 256² tile would underfill the grid)
template <int OUT_BF16>
__global__ __launch_bounds__(256) void gemm_bt(const u16* __restrict__ A,
                                               const u16* __restrict__ B,
                                               void* __restrict__ Cv,
                                               int M, int N, int K) {
  __shared__ __align__(16) u16 lA[128 * 32];
  __shared__ __align__(16) u16 lB[128 * 32];
  const int tid = threadIdx.x;
  const int lane = tid & 63;
  const int w = tid >> 6;
  const int wr = (w >> 1) * 64;
  const int wc = (w & 1) * 64;
  const int fr = lane & 15;
  const int fq = lane >> 4;
  const int row0 = blockIdx.x * 128;
  const int col0 = blockIdx.y * 128;

  const f32x4 z4 = {0.f, 0.f, 0.f, 0.f};
  f32x4 acc[4][4];
#pragma unroll
  for (int m = 0; m < 4; ++m)
#pragma unroll
    for (int n = 0; n < 4; ++n) acc[m][n] = z4;

  const int sr = tid >> 2;
  const int sc = (tid & 3) * 8;

  for (int k0 = 0; k0 < K; k0 += 32) {
    __syncthreads();
#pragma unroll
    for (int rep = 0; rep < 2; ++rep) {
      const int row = rep * 64 + sr;
      const int ldsbase = (rep * 256 + w * 64) * 8;
      gload16(lA + ldsbase, A + (size_t)(row0 + row) * K + (k0 + sc));
      gload16(lB + ldsbase, B + (size_t)(col0 + row) * K + (k0 + sc));
    }
    __syncthreads();

    bf16x8 af[4], bfr[4];
#pragma unroll
    for (int m = 0; m < 4; ++m)
      af[m] = *reinterpret_cast<const bf16x8*>(lA + (wr + m * 16 + fr) * 32 + fq * 8);
#pragma unroll
    for (int n = 0; n < 4; ++n)
      bfr[n] = *reinterpret_cast<const bf16x8*>(lB + (wc + n * 16 + fr) * 32 + fq * 8);
#pragma unroll
    for (int m = 0; m < 4; ++m)
#pragma unroll
      for (int n = 0; n < 4; ++n)
        acc[m][n] = __builtin_amdgcn_mfma_f32_16x16x32_bf16(af[m], bfr[n], acc[m][n], 0, 0, 0);
  }

#pragma unroll
  for (int m = 0; m < 4; ++m) {
    const int grow0 = row0 + wr + m * 16 + fq * 4;
#pragma unroll
    for (int n = 0; n < 4; ++n) {
      const int gcol = col0 + wc + n * 16 + fr;
#pragma unroll
      for (int j = 0; j < 4; ++j) {
        const size_t off = (size_t)(grow0 + j) * N + gcol;
        if (OUT_BF16) ((u16*)Cv)[off] = f2bf(acc[m][n][j]);
        else          ((float*)Cv)[off] = acc[m][n][j];
      }
    }
  }
}

// ---------------------------------------------------------------- GEMM (256²,8ph)
// 8-phase template: BM=BN=256, BK=64, 8 waves (2M x 4N), per-wave C = 128x64.
// LDS 128 KiB double-buffer. T2 swizzle: linear gload_lds dest, inverse-swizzled
// global source col, swizzled ds_read. T4: counted vmcnt(2)/vmcnt(4). T5 setprio.
template <int OUT_BF16>
__global__ __launch_bounds__(512, 2) void gemm256(const u16* __restrict__ A,
                                                  const u16* __restrict__ B,
                                                  void* __restrict__ Cv,
                                                  int M, int N, int K) {
  __shared__ __align__(16) u16 sA[2][16384];   // [256 rows][64 cols] x dbuf
  __shared__ __align__(16) u16 sB[2][16384];
  const int tid = threadIdx.x;                 // 0..511
  const int lane = tid & 63, w = tid >> 6;
  const int wm = w >> 2, wn = w & 3;           // wave grid 2M x 4N
  const int fr = lane & 15, fq = lane >> 4;
  const int r0 = blockIdx.x * 256, c0 = blockIdx.y * 256;

  // staging: chunk c covers LDS elems [c*4096, +4096) = rows [c*64, +64).
  // lane slot idx = c*512 + tid; row = idx>>3, slot = idx&7.
  // inverse-swizzled global col so that swizzled read is linear-correct.
  const u16* aSrc[4];
  const u16* bSrc[4];
#pragma unroll
  for (int c = 0; c < 4; ++c) {
    const int idx = c * 512 + tid;
    const int row = idx >> 3;
    const int col = ((idx & 7) ^ (row & 7)) * 8;
    aSrc[c] = A + (size_t)(r0 + row) * K + col;
    bSrc[c] = B + (size_t)(c0 + row) * K + col;
  }

  // ds_read swizzled k-slot byte offsets (elems): slot = (ks*4+fq) ^ (fr&7)
  const int sw0 = ((fq) ^ (fr & 7)) * 8;
  const int sw1 = ((4 + fq) ^ (fr & 7)) * 8;
  const int aB = wm * 8192 + fr * 64;          // + m*1024 + sw[ks]
  const int bB = wn * 4096 + fr * 64;          // + n*1024 + sw[ks]

  const f32x4 z4 = {0.f, 0.f, 0.f, 0.f};
  f32x4 acc[8][4];
#pragma unroll
  for (int m = 0; m < 8; ++m)
#pragma unroll
    for (int n = 0; n < 4; ++n) acc[m][n] = z4;

  const int NT = K >> 6;

#define SG(arr, src, c, buf, ko) \
  gload16(&arr[buf][(c * 512 + w * 64) * 8], src[c] + (ko))

  // prologue: tile 0 -> buf0. Issue order B0 B1 B2 B3 A0 A2 A1 A3
  SG(sB, bSrc, 0, 0, 0); SG(sB, bSrc, 1, 0, 0);
  SG(sB, bSrc, 2, 0, 0); SG(sB, bSrc, 3, 0, 0);
  SG(sA, aSrc, 0, 0, 0); SG(sA, aSrc, 2, 0, 0);
  SG(sA, aSrc, 1, 0, 0); SG(sA, aSrc, 3, 0, 0);

  for (int u = 0; u < NT; ++u) {
    const int par = u & 1, nxt = par ^ 1;
    const u16* a = sA[par];
    const u16* b = sB[par];
    const bool pf = (u + 1 < NT);
    const size_t ko = (size_t)(u + 1) * 64;
    bf16x8 bf[4][2], af[2][2];

#define RD_A(p)                                                              \
  _Pragma("unroll") for (int i = 0; i < 2; ++i) {                            \
    af[i][0] = *(const bf16x8*)(a + aB + (2 * (p) + i) * 1024 + sw0);        \
    af[i][1] = *(const bf16x8*)(a + aB + (2 * (p) + i) * 1024 + sw1);        \
  }
#define MM(p)                                                                \
  __builtin_amdgcn_s_setprio(1);                                             \
  _Pragma("unroll") for (int i = 0; i < 2; ++i)                              \
  _Pragma("unroll") for (int n = 0; n < 4; ++n)                              \
  _Pragma("unroll") for (int ks = 0; ks < 2; ++ks)                           \
    acc[2 * (p) + i][n] = __builtin_amdgcn_mfma_f32_16x16x32_bf16(           \
        af[i][ks], bf[n][ks], acc[2 * (p) + i][n], 0, 0, 0);                 \
  __builtin_amdgcn_s_setprio(0);

    // ---------- phase 0 : B(all) + A m0,1 ; stage B0,B1(u+1)
    asm volatile("s_waitcnt vmcnt(2)" ::: "memory");
    __builtin_amdgcn_s_barrier();
#pragma unroll
    for (int n = 0; n < 4; ++n) {
      bf[n][0] = *(const bf16x8*)(b + bB + n * 1024 + sw0);
      bf[n][1] = *(const bf16x8*)(b + bB + n * 1024 + sw1);
    }
    RD_A(0)
    if (pf) { SG(sB, bSrc, 0, nxt, ko); SG(sB, bSrc, 1, nxt, ko); }
    __builtin_amdgcn_s_barrier();
    MM(0)
    __builtin_amdgcn_s_barrier();

    // ---------- phase 1 : A m2,3 ; stage B2,B3(u+1)
    RD_A(1)
    if (pf) { SG(sB, bSrc, 2, nxt, ko); SG(sB, bSrc, 3, nxt, ko); }
    __builtin_amdgcn_s_barrier();
    MM(1)
    __builtin_amdgcn_s_barrier();

    // ---------- phase 2 : A m4,5 ; stage A0,A2(u+1)
    if (pf) { asm volatile("s_waitcnt vmcnt(4)" ::: "memory"); }
    else    { asm volatile("s_waitcnt vmcnt(0)" ::: "memory"); }
    RD_A(2)
    if (pf) { SG(sA, aSrc, 0, nxt, ko); SG(sA, aSrc, 2, nxt, ko); }
    __builtin_amdgcn_s_barrier();
    MM(2)
    __builtin_amdgcn_s_barrier();

    // ---------- phase 3 : A m6,7 ; stage A1,A3(u+1)
    RD_A(3)
    if (pf) { SG(sA, aSrc, 1, nxt, ko); SG(sA, aSrc, 3, nxt, ko); }
    __builtin_amdgcn_s_barrier();
    MM(3)
    __builtin_amdgcn_s_barrier();
#undef RD_A
#undef MM
  }
#undef SG

  // epilogue: C[row = r0+wm*128+m*16+fq*4+j][col = c0+wn*64+n*16+fr]
#pragma unroll
  for (int m = 0; m < 8; ++m) {
    const int gr = r0 + wm * 128 + m * 16 + fq * 4;
#pragma unroll
    for (int n = 0; n < 4; ++n) {
      const int gc = c0 + wn * 64 + n * 16 + fr;
#pragma unroll
      for (int j = 0; j < 4; ++j) {
        const size_t off = (size_t)(gr + j) * N + gc;
        if (OUT_BF16) ((u16*)Cv)[off] = f2bf(acc[m][n][j]);
        else          ((float*)Cv)[off] = acc[m][n][j];
      }
    }
  }
}

// ---------------------------------------------------------------- 3D RoPE on q,k
__global__ __launch_bounds__(256) void rope_kernel(u16* __restrict__ qkv,
                                                   const float* __restrict__ Rs) {
  const int bid = blockIdx.x;        // [0, 8192)
  const int qk = bid & 1;
  const int bt = bid >> 1;
  const int t = bt & 2047;
  const int tid = threadIdx.x;

  __shared__ __align__(16) u16 buf[1536];
  __shared__ __align__(16) float rbuf[288];

  u16* g = qkv + (size_t)bt * 4608 + qk * 1536;
  if (tid < 192)
    *reinterpret_cast<uint4*>(buf + tid * 8) = *reinterpret_cast<const uint4*>(g + tid * 8);
  if (tid < 72)
    *reinterpret_cast<float4*>(rbuf + tid * 4) =
        *reinterpret_cast<const float4*>(Rs + (size_t)t * 288 + tid * 4);
  __syncthreads();

#pragma unroll
  for (int rep = 0; rep < 2; ++rep) {
    const int ft = rep * 256 + tid;
    const int base = (ft >> 5) * 96 + (ft & 31) * 3;
    const float* R = rbuf + (ft & 31) * 9;
    const float x0 = bf2f(buf[base]), x1 = bf2f(buf[base + 1]), x2 = bf2f(buf[base + 2]);
    const float y0 = R[0] * x0 + R[1] * x1 + R[2] * x2;
    const float y1 = R[3] * x0 + R[4] * x1 + R[5] * x2;
    const float y2 = R[6] * x0 + R[7] * x1 + R[8] * x2;
    buf[base] = f2bf(y0); buf[base + 1] = f2bf(y1); buf[base + 2] = f2bf(y2);
  }
  __syncthreads();
  if (tid < 192)
    *reinterpret_cast<uint4*>(g + tid * 8) = *reinterpret_cast<const uint4*>(buf + tid * 8);
}

// ---------------------------------------------------------------- KV fragment prep
__global__ __launch_bounds__(256) void kvprep(const u16* __restrict__ qkv,
                                              u16* __restrict__ Kf,
                                              u16* __restrict__ Vf) {
  const int kt = blockIdx.x, bh = blockIdx.y;
  const int b = bh >> 4, h = bh & 15;
  const int tid = threadIdx.x, lane = tid & 63, w = tid >> 6;
  const float SC = 0.14724574f;  // (1/sqrt(96)) * log2(e)
  __shared__ __align__(16) u16 vlds[64 * 96];

#pragma unroll
  for (int r = 0; r < 3; ++r) {
    const int idx = r * 256 + tid;
    const int kv = idx / 12, c8 = (idx % 12) * 8;
    gload16(vlds + (r * 256 + w * 64) * 8,
            qkv + (size_t)(b * 2048 + kt * 64 + kv) * 4608 + 3072 + h * 96 + c8);
  }

  const size_t obase = ((size_t)bh * 32 + kt) * 6144;
#pragma unroll
  for (int r = 0; r < 3; ++r) {
    const int chunk = r * 256 + tid;
    const int sub = chunk >> 6, l = chunk & 63;
    const int m = sub / 3, kb = sub % 3;
    const int fr = l & 15, fq = l >> 4;
    uint4 v = *reinterpret_cast<const uint4*>(
        qkv + (size_t)(b * 2048 + kt * 64 + m * 16 + fr) * 4608 + 1536 + h * 96 + kb * 32 + fq * 8);
    u16* p = reinterpret_cast<u16*>(&v);
#pragma unroll
    for (int e = 0; e < 8; ++e) p[e] = f2bf(bf2f(p[e]) * SC);
    *reinterpret_cast<uint4*>(Kf + obase + (size_t)chunk * 8) = v;
  }
  __syncthreads();
#pragma unroll
  for (int r = 0; r < 3; ++r) {
    const int chunk = r * 256 + tid;
    const int sub = chunk >> 6, l = chunk & 63;
    const int n2 = sub >> 1, c = sub & 1;
    const int fr = l & 15, fq = l >> 4;
    const int d = n2 * 16 + fr;
    u16 out[8];
#pragma unroll
    for (int e = 0; e < 8; ++e) {
      const int kl = (c * 2 + (e >> 2)) * 16 + fq * 4 + (e & 3);
      out[e] = vlds[kl * 96 + d];
    }
    *reinterpret_cast<uint4*>(Vf + obase + (size_t)chunk * 8) =
        *reinterpret_cast<uint4*>(out);
  }
}

// ---------------------------------------------------------------- flash attention
__global__ __launch_bounds__(256, 2) void attn_fwd(const u16* __restrict__ qkvb,
                                                   const u16* __restrict__ Kf,
                                                   const u16* __restrict__ Vf,
                                                   u16* __restrict__ y) {
  const int bh = blockIdx.x;
  const int qt = 15 - (int)blockIdx.y;   // LPT: heavy blocks dispatched first
  const int b = bh >> 4, h = bh & 15;
  const int tid = threadIdx.x, lane = tid & 63, w = tid >> 6;
  const int fr = lane & 15, fq = lane >> 4;
  const int q0 = qt * 128;
  const int qw = q0 + w * 32;            // wave's first q row

  __shared__ __align__(16) u16 kbl[2][6144];
  __shared__ __align__(16) u16 vbl[2][6144];

  bf16x8 qf[2][3];
#pragma unroll
  for (int nq = 0; nq < 2; ++nq)
#pragma unroll
    for (int kb = 0; kb < 3; ++kb)
      qf[nq][kb] = *reinterpret_cast<const bf16x8*>(
          qkvb + (size_t)(b * 2048 + qw + nq * 16 + fr) * 4608 + h * 96 + kb * 32 + fq * 8);

  const f32x4 z4 = {0.f, 0.f, 0.f, 0.f};
  f32x4 oacc[2][6];
#pragma unroll
  for (int mq = 0; mq < 2; ++mq)
#pragma unroll
    for (int n2 = 0; n2 < 6; ++n2) oacc[mq][n2] = z4;
  float mrow[2] = {-1e30f, -1e30f}, ssum[2] = {0.f, 0.f};

  const int nt = 2 * qt + 2;
  const size_t tb = (size_t)bh * 32 * 6144;

#define STAGE(buf, kt_)                                                         \
  do {                                                                          \
    const size_t sb = tb + (size_t)(kt_)*6144;                                  \
    _Pragma("unroll") for (int r = 0; r < 3; ++r) {                             \
      gload16(kbl[buf] + (r * 256 + w * 64) * 8, Kf + sb + (r * 256 + w * 64 + lane) * 8); \
      gload16(vbl[buf] + (r * 256 + w * 64) * 8, Vf + sb + (r * 256 + w * 64 + lane) * 8); \
    }                                                                           \
  } while (0)

  STAGE(0, 0);
  for (int kt = 0; kt < nt; ++kt) {
    __syncthreads();                     // stage(kt) landed; compute(kt-1) done
    if (kt + 1 < nt) STAGE((kt + 1) & 1, kt + 1);
    const u16* kc = kbl[kt & 1];
    const u16* vc = vbl[kt & 1];
    const int k0 = kt * 64;

    if (k0 <= qw + 31) {                 // wave has unmasked work (wave-uniform)
      f32x4 sacc[4][2];
#pragma unroll
      for (int m = 0; m < 4; ++m)
#pragma unroll
        for (int nq = 0; nq < 2; ++nq) sacc[m][nq] = z4;
#pragma unroll
      for (int kb = 0; kb < 3; ++kb)
#pragma unroll
        for (int m = 0; m < 4; ++m) {
          const bf16x8 kfrag = *reinterpret_cast<const bf16x8*>(kc + ((m * 3 + kb) * 64 + lane) * 8);
#pragma unroll
          for (int nq = 0; nq < 2; ++nq)
            sacc[m][nq] = __builtin_amdgcn_mfma_f32_16x16x32_bf16(kfrag, qf[nq][kb], sacc[m][nq], 0, 0, 0);
        }
      if (k0 + 63 > qw) {
#pragma unroll
        for (int m = 0; m < 4; ++m) {
          const int kpos = k0 + m * 16 + fq * 4;
#pragma unroll
          for (int nq = 0; nq < 2; ++nq) {
            const int qpos = qw + nq * 16 + fr;
#pragma unroll
            for (int j = 0; j < 4; ++j)
              if (kpos + j > qpos) sacc[m][nq][j] = -1e30f;
          }
        }
      }
      float al[2];
#pragma unroll
      for (int nq = 0; nq < 2; ++nq) {
        float mx = sacc[0][nq][0];
#pragma unroll
        for (int m = 0; m < 4; ++m)
#pragma unroll
          for (int j = 0; j < 4; ++j) mx = fmaxf(mx, sacc[m][nq][j]);
        mx = fmaxf(mx, __shfl_xor(mx, 16));
        mx = fmaxf(mx, __shfl_xor(mx, 32));
        const float mn = fmaxf(mrow[nq], mx);
        al[nq] = exp2f_fast(mrow[nq] - mn);
        mrow[nq] = mn;
        float s = 0.f;
#pragma unroll
        for (int m = 0; m < 4; ++m) {
          f32x4 p;
#pragma unroll
          for (int j = 0; j < 4; ++j) p[j] = exp2f_fast(sacc[m][nq][j] - mn);
          sacc[m][nq] = p;
          s += (p[0] + p[1]) + (p[2] + p[3]);
        }
        s += __shfl_xor(s, 16);
        s += __shfl_xor(s, 32);
        ssum[nq] = ssum[nq] * al[nq] + s;
      }
      float alb[2][4];
#pragma unroll
      for (int mq = 0; mq < 2; ++mq)
#pragma unroll
        for (int j = 0; j < 4; ++j) alb[mq][j] = __shfl(al[mq], fq * 4 + j);
#pragma unroll
      for (int mq = 0; mq < 2; ++mq)
#pragma unroll
        for (int n2 = 0; n2 < 6; ++n2) {
          f32x4 t = oacc[mq][n2];
          t[0] *= alb[mq][0]; t[1] *= alb[mq][1]; t[2] *= alb[mq][2]; t[3] *= alb[mq][3];
          oacc[mq][n2] = t;
        }
      union PB { u32 u[4]; bf16x8 v; };
      PB pa[2][2];
#pragma unroll
      for (int c = 0; c < 2; ++c)
#pragma unroll
        for (int mq = 0; mq < 2; ++mq) {
          pa[c][mq].u[0] = cvtpk(sacc[2 * c][mq][0], sacc[2 * c][mq][1]);
          pa[c][mq].u[1] = cvtpk(sacc[2 * c][mq][2], sacc[2 * c][mq][3]);
          pa[c][mq].u[2] = cvtpk(sacc[2 * c + 1][mq][0], sacc[2 * c + 1][mq][1]);
          pa[c][mq].u[3] = cvtpk(sacc[2 * c + 1][mq][2], sacc[2 * c + 1][mq][3]);
        }
#pragma unroll
      for (int c = 0; c < 2; ++c)
#pragma unroll
        for (int n2 = 0; n2 < 6; ++n2) {
          const bf16x8 vfrag = *reinterpret_cast<const bf16x8*>(vc + ((n2 * 2 + c) * 64 + lane) * 8);
#pragma unroll
          for (int mq = 0; mq < 2; ++mq)
            oacc[mq][n2] = __builtin_amdgcn_mfma_f32_16x16x32_bf16(pa[c][mq].v, vfrag, oacc[mq][n2], 0, 0, 0);
        }
    }
  }
#undef STAGE

  float inv[2][4];
#pragma unroll
  for (int mq = 0; mq < 2; ++mq)
#pragma unroll
    for (int j = 0; j < 4; ++j)
      inv[mq][j] = __builtin_amdgcn_rcpf(__shfl(ssum[mq], fq * 4 + j));
#pragma unroll
  for (int mq = 0; mq < 2; ++mq)
#pragma unroll
    for (int n2 = 0; n2 < 6; ++n2)
#pragma unroll
      for (int j = 0; j < 4; ++j) {
        const size_t off =
            (size_t)(b * 2048 + qw + mq * 16 + fq * 4 + j) * 1536 + h * 96 + n2 * 16 + fr;
        y[off] = f2bf(oacc[mq][n2][j] * inv[mq][j]);
      }
}

// ---------------------------------------------------------------- launch
extern "C" void kernel_launch(void* const* d_in, const int* in_sizes, int n_in,
                              void* d_out, int out_size, void* d_ws, size_t ws_size,
                              hipStream_t stream) {
  (void)in_sizes; (void)n_in; (void)out_size; (void)ws_size;
  const float* x     = (const float*)d_in[0];
  const float* w_qkv = (const float*)d_in[1];
  const float* w_o   = (const float*)d_in[2];
  const float* Rs    = (const float*)d_in[3];
  float* out = (float*)d_out;

  // ws layout (u16 elems). Kf/Vf alias xb/wqkvb (dead after gemm1). Total 81.8 MB.
  u16* xb    = (u16*)d_ws;            // 6291456
  u16* wqkvb = xb + 6291456;          // 7077888
  u16* wob   = xb + 13369344;         // 2359296
  u16* qkvb  = xb + 15728640;         // 18874368
  u16* yb    = xb + 34603008;         // 6291456
  u16* Kf    = xb;                    // 6291456 (32 bh x 32 kt x 6144)
  u16* Vf    = xb + 6291456;          // 6291456

  cvt_bf16<<<1572864 / 256, 256, 0, stream>>>(x, xb, 1572864);
  cvt_bf16<<<1769472 / 256, 256, 0, stream>>>(w_qkv, wqkvb, 1769472);
  cvt_bf16<<<589824 / 256, 256, 0, stream>>>(w_o, wob, 589824);

  gemm256<1><<<dim3(16, 18), 512, 0, stream>>>(xb, wqkvb, (void*)qkvb, 4096, 4608, 1536);
  rope_kernel<<<8192, 256, 0, stream>>>(qkvb, Rs);
  kvprep<<<dim3(32, 32), 256, 0, stream>>>(qkvb, Kf, Vf);
  attn_fwd<<<dim3(32, 16), 256, 0, stream>>>(qkvb, Kf, Vf, yb);
  gemm_bt<0><<<dim3(32, 12), 256, 0, stream>>>(yb, wob, (void*)out, 4096, 1536, 1536);
}

// Round 5
// 295.334 us; speedup vs baseline: 1.1194x; 1.1194x over previous
//
#include <hip/hip_runtime.h>
#include <stdint.h>

// B=2, T=2048, D_MODEL=1536, H=16, hd=96, n_trip=32. qkv row = 4608, rows = 4096.

typedef unsigned short u16;
typedef unsigned int u32;
typedef __attribute__((ext_vector_type(8))) __bf16 bf16x8;   // MFMA A/B frag
typedef __attribute__((ext_vector_type(4))) float f32x4;     // MFMA C/D frag

#define DEV static __device__ __forceinline__

DEV u16 f2bf(float f) {
  u32 u = __float_as_uint(f);
  return (u16)((u + 0x7fffu + ((u >> 16) & 1u)) >> 16);  // RNE
}
DEV float bf2f(u16 h) { return __uint_as_float(((u32)h) << 16); }
DEV u32 cvtpk(float lo, float hi) {  // packed f32->bf16 pair (lo->bits[15:0])
  u32 r;
  asm("v_cvt_pk_bf16_f32 %0, %1, %2" : "=v"(r) : "v"(lo), "v"(hi));
  return r;
}
DEV float exp2f_fast(float x) {
  float r;
  asm("v_exp_f32 %0, %1" : "=v"(r) : "v"(x));
  return r;
}

// async global->LDS, 16B/lane. LDS dest = wave-uniform base + lane*16.
DEV void gload16(u16* lds_dst, const u16* gsrc) {
  __builtin_amdgcn_global_load_lds(
      (const __attribute__((address_space(1))) void*)gsrc,
      (__attribute__((address_space(3))) void*)lds_dst, 16, 0, 0);
}

// ---------------------------------------------------------------- cvt f32->bf16
__global__ __launch_bounds__(256) void cvt_bf16(const float* __restrict__ in,
                                                u16* __restrict__ out, int n4) {
  int i = blockIdx.x * 256 + threadIdx.x;
  if (i < n4) {
    float4 v = reinterpret_cast<const float4*>(in)[i];
    ushort4 o;
    o.x = f2bf(v.x); o.y = f2bf(v.y); o.z = f2bf(v.z); o.w = f2bf(v.w);
    reinterpret_cast<ushort4*>(out)[i] = o;
  }
}

// ---------------------------------------------------------------- GEMM (128x192)
// Balanced-fill pipelined GEMM: C = A * B^T. BM=128, BN=192, BK=64.
// grid = (M/128, N/192); gemm1: 768 = 3*256 blocks, gemm2: 256 blocks.
// LDS 80 KiB (dbuf) -> 2 blocks/CU. 8 waves as 2M x 4N -> wave tile 64x48.
// T2 swizzle identical to verified gemm256 (source-permutation == read-
// permutation: slot = (ks*4+fq) ^ (fr&7); valid since 48 % 8 == 0).
// T4 counted vmcnt: per-tile issue [A0 A1 | B0 B1 B2]; gates vmcnt(3)/vmcnt(2).
template <int OUT_BF16>
__global__ __launch_bounds__(512, 4) void gemm_bal(const u16* __restrict__ A,
                                                   const u16* __restrict__ B,
                                                   void* __restrict__ Cv,
                                                   int M, int N, int K) {
  (void)M;
  __shared__ __align__(16) u16 sA[2][128 * 64];   // 16 KiB per buf
  __shared__ __align__(16) u16 sB[2][192 * 64];   // 24 KiB per buf
  const int tid = threadIdx.x;                    // 0..511
  const int lane = tid & 63, w = tid >> 6;
  const int wm = w >> 2, wn = w & 3;              // wave grid 2M x 4N
  const int fr = lane & 15, fq = lane >> 4;
  const int r0 = blockIdx.x * 128, c0 = blockIdx.y * 192;

  // staging sources: chunk c covers LDS rows [c*64, +64); idx = c*512+tid;
  // row = idx>>3, slot = idx&7; global col inverse-swizzled.
  const u16* aSrc[2];
  const u16* bSrc[3];
#pragma unroll
  for (int c = 0; c < 2; ++c) {
    const int idx = c * 512 + tid;
    const int row = idx >> 3;
    aSrc[c] = A + (size_t)(r0 + row) * K + ((idx & 7) ^ (row & 7)) * 8;
  }
#pragma unroll
  for (int c = 0; c < 3; ++c) {
    const int idx = c * 512 + tid;
    const int row = idx >> 3;
    bSrc[c] = B + (size_t)(c0 + row) * K + ((idx & 7) ^ (row & 7)) * 8;
  }

  // swizzled ds_read k-slot offsets (elems): slot = (ks*4+fq) ^ (fr&7)
  const int sw0 = ((fq) ^ (fr & 7)) * 8;
  const int sw1 = ((4 + fq) ^ (fr & 7)) * 8;
  const int aB = (wm * 64 + fr) * 64;             // + m*1024 + sw[ks]
  const int bB = (wn * 48 + fr) * 64;             // + n*1024 + sw[ks]

  const f32x4 z4 = {0.f, 0.f, 0.f, 0.f};
  f32x4 acc[4][3];
#pragma unroll
  for (int m = 0; m < 4; ++m)
#pragma unroll
    for (int n = 0; n < 3; ++n) acc[m][n] = z4;

  const int NT = K >> 6;

#define SGA(c, buf, ko) gload16(&sA[buf][((c)*512 + w * 64) * 8], aSrc[c] + (ko))
#define SGB(c, buf, ko) gload16(&sB[buf][((c)*512 + w * 64) * 8], bSrc[c] + (ko))

  // prologue: tile 0 -> buf0, order A0 A1 B0 B1 B2
  SGA(0, 0, 0); SGA(1, 0, 0);
  SGB(0, 0, 0); SGB(1, 0, 0); SGB(2, 0, 0);

  for (int u = 0; u < NT; ++u) {
    const int par = u & 1, nxt = par ^ 1;
    const u16* a = sA[par];
    const u16* b = sB[par];
    const bool pf = (u + 1 < NT);
    const size_t ko = (size_t)(u + 1) * 64;

    // ---- sub-phase 0: retire A(u); prefetch A(u+1)
    asm volatile("s_waitcnt vmcnt(3)" ::: "memory");
    __builtin_amdgcn_s_barrier();
    if (pf) { SGA(0, nxt, ko); SGA(1, nxt, ko); }

    // ---- sub-phase 1: retire B(u); read frags; prefetch B(u+1); MFMA
    if (pf) { asm volatile("s_waitcnt vmcnt(2)" ::: "memory"); }
    else    { asm volatile("s_waitcnt vmcnt(0)" ::: "memory"); }
    __builtin_amdgcn_s_barrier();
    bf16x8 bfr[3][2];
#pragma unroll
    for (int n = 0; n < 3; ++n) {
      bfr[n][0] = *(const bf16x8*)(b + bB + n * 1024 + sw0);
      bfr[n][1] = *(const bf16x8*)(b + bB + n * 1024 + sw1);
    }
    if (pf) { SGB(0, nxt, ko); SGB(1, nxt, ko); SGB(2, nxt, ko); }
    __builtin_amdgcn_s_barrier();
    __builtin_amdgcn_s_setprio(1);
#pragma unroll
    for (int mp = 0; mp < 2; ++mp) {
      bf16x8 afr[2][2];
#pragma unroll
      for (int i = 0; i < 2; ++i) {
        afr[i][0] = *(const bf16x8*)(a + aB + (2 * mp + i) * 1024 + sw0);
        afr[i][1] = *(const bf16x8*)(a + aB + (2 * mp + i) * 1024 + sw1);
      }
#pragma unroll
      for (int i = 0; i < 2; ++i)
#pragma unroll
        for (int n = 0; n < 3; ++n)
#pragma unroll
          for (int ks = 0; ks < 2; ++ks)
            acc[2 * mp + i][n] = __builtin_amdgcn_mfma_f32_16x16x32_bf16(
                afr[i][ks], bfr[n][ks], acc[2 * mp + i][n], 0, 0, 0);
    }
    __builtin_amdgcn_s_setprio(0);
  }
#undef SGA
#undef SGB

  // epilogue: C[row = r0+wm*64+m*16+fq*4+j][col = c0+wn*48+n*16+fr]
#pragma unroll
  for (int m = 0; m < 4; ++m) {
    const int gr = r0 + wm * 64 + m * 16 + fq * 4;
#pragma unroll
    for (int n = 0; n < 3; ++n) {
      const int gc = c0 + wn * 48 + n * 16 + fr;
#pragma unroll
      for (int j = 0; j < 4; ++j) {
        const size_t off = (size_t)(gr + j) * N + gc;
        if (OUT_BF16) ((u16*)Cv)[off] = f2bf(acc[m][n][j]);
        else          ((float*)Cv)[off] = acc[m][n][j];
      }
    }
  }
}

// ---------------------------------------------------------------- 3D RoPE on q,k
__global__ __launch_bounds__(256) void rope_kernel(u16* __restrict__ qkv,
                                                   const float* __restrict__ Rs) {
  const int bid = blockIdx.x;        // [0, 8192)
  const int qk = bid & 1;
  const int bt = bid >> 1;
  const int t = bt & 2047;
  const int tid = threadIdx.x;

  __shared__ __align__(16) u16 buf[1536];
  __shared__ __align__(16) float rbuf[288];

  u16* g = qkv + (size_t)bt * 4608 + qk * 1536;
  if (tid < 192)
    *reinterpret_cast<uint4*>(buf + tid * 8) = *reinterpret_cast<const uint4*>(g + tid * 8);
  if (tid < 72)
    *reinterpret_cast<float4*>(rbuf + tid * 4) =
        *reinterpret_cast<const float4*>(Rs + (size_t)t * 288 + tid * 4);
  __syncthreads();

#pragma unroll
  for (int rep = 0; rep < 2; ++rep) {
    const int ft = rep * 256 + tid;
    const int base = (ft >> 5) * 96 + (ft & 31) * 3;
    const float* R = rbuf + (ft & 31) * 9;
    const float x0 = bf2f(buf[base]), x1 = bf2f(buf[base + 1]), x2 = bf2f(buf[base + 2]);
    const float y0 = R[0] * x0 + R[1] * x1 + R[2] * x2;
    const float y1 = R[3] * x0 + R[4] * x1 + R[5] * x2;
    const float y2 = R[6] * x0 + R[7] * x1 + R[8] * x2;
    buf[base] = f2bf(y0); buf[base + 1] = f2bf(y1); buf[base + 2] = f2bf(y2);
  }
  __syncthreads();
  if (tid < 192)
    *reinterpret_cast<uint4*>(g + tid * 8) = *reinterpret_cast<const uint4*>(buf + tid * 8);
}

// ---------------------------------------------------------------- KV fragment prep
__global__ __launch_bounds__(256) void kvprep(const u16* __restrict__ qkv,
                                              u16* __restrict__ Kf,
                                              u16* __restrict__ Vf) {
  const int kt = blockIdx.x, bh = blockIdx.y;
  const int b = bh >> 4, h = bh & 15;
  const int tid = threadIdx.x, lane = tid & 63, w = tid >> 6;
  const float SC = 0.14724574f;  // (1/sqrt(96)) * log2(e)
  __shared__ __align__(16) u16 vlds[64 * 96];

#pragma unroll
  for (int r = 0; r < 3; ++r) {
    const int idx = r * 256 + tid;
    const int kv = idx / 12, c8 = (idx % 12) * 8;
    gload16(vlds + (r * 256 + w * 64) * 8,
            qkv + (size_t)(b * 2048 + kt * 64 + kv) * 4608 + 3072 + h * 96 + c8);
  }

  const size_t obase = ((size_t)bh * 32 + kt) * 6144;
#pragma unroll
  for (int r = 0; r < 3; ++r) {
    const int chunk = r * 256 + tid;
    const int sub = chunk >> 6, l = chunk & 63;
    const int m = sub / 3, kb = sub % 3;
    const int fr = l & 15, fq = l >> 4;
    uint4 v = *reinterpret_cast<const uint4*>(
        qkv + (size_t)(b * 2048 + kt * 64 + m * 16 + fr) * 4608 + 1536 + h * 96 + kb * 32 + fq * 8);
    u16* p = reinterpret_cast<u16*>(&v);
#pragma unroll
    for (int e = 0; e < 8; ++e) p[e] = f2bf(bf2f(p[e]) * SC);
    *reinterpret_cast<uint4*>(Kf + obase + (size_t)chunk * 8) = v;
  }
  __syncthreads();
#pragma unroll
  for (int r = 0; r < 3; ++r) {
    const int chunk = r * 256 + tid;
    const int sub = chunk >> 6, l = chunk & 63;
    const int n2 = sub >> 1, c = sub & 1;
    const int fr = l & 15, fq = l >> 4;
    const int d = n2 * 16 + fr;
    u16 out[8];
#pragma unroll
    for (int e = 0; e < 8; ++e) {
      const int kl = (c * 2 + (e >> 2)) * 16 + fq * 4 + (e & 3);
      out[e] = vlds[kl * 96 + d];
    }
    *reinterpret_cast<uint4*>(Vf + obase + (size_t)chunk * 8) =
        *reinterpret_cast<uint4*>(out);
  }
}

// ---------------------------------------------------------------- flash attention
__global__ __launch_bounds__(256, 2) void attn_fwd(const u16* __restrict__ qkvb,
                                                   const u16* __restrict__ Kf,
                                                   const u16* __restrict__ Vf,
                                                   u16* __restrict__ y) {
  const int bh = blockIdx.x;
  const int qt = 15 - (int)blockIdx.y;   // LPT: heavy blocks dispatched first
  const int b = bh >> 4, h = bh & 15;
  const int tid = threadIdx.x, lane = tid & 63, w = tid >> 6;
  const int fr = lane & 15, fq = lane >> 4;
  const int q0 = qt * 128;
  const int qw = q0 + w * 32;            // wave's first q row

  __shared__ __align__(16) u16 kbl[2][6144];
  __shared__ __align__(16) u16 vbl[2][6144];

  bf16x8 qf[2][3];
#pragma unroll
  for (int nq = 0; nq < 2; ++nq)
#pragma unroll
    for (int kb = 0; kb < 3; ++kb)
      qf[nq][kb] = *reinterpret_cast<const bf16x8*>(
          qkvb + (size_t)(b * 2048 + qw + nq * 16 + fr) * 4608 + h * 96 + kb * 32 + fq * 8);

  const f32x4 z4 = {0.f, 0.f, 0.f, 0.f};
  f32x4 oacc[2][6];
#pragma unroll
  for (int mq = 0; mq < 2; ++mq)
#pragma unroll
    for (int n2 = 0; n2 < 6; ++n2) oacc[mq][n2] = z4;
  float mrow[2] = {-1e30f, -1e30f}, ssum[2] = {0.f, 0.f};

  const int nt = 2 * qt + 2;
  const size_t tb = (size_t)bh * 32 * 6144;

#define STAGE(buf, kt_)                                                         \
  do {                                                                          \
    const size_t sb = tb + (size_t)(kt_)*6144;                                  \
    _Pragma("unroll") for (int r = 0; r < 3; ++r) {                             \
      gload16(kbl[buf] + (r * 256 + w * 64) * 8, Kf + sb + (r * 256 + w * 64 + lane) * 8); \
      gload16(vbl[buf] + (r * 256 + w * 64) * 8, Vf + sb + (r * 256 + w * 64 + lane) * 8); \
    }                                                                           \
  } while (0)

  STAGE(0, 0);
  for (int kt = 0; kt < nt; ++kt) {
    __syncthreads();                     // stage(kt) landed; compute(kt-1) done
    if (kt + 1 < nt) STAGE((kt + 1) & 1, kt + 1);
    const u16* kc = kbl[kt & 1];
    const u16* vc = vbl[kt & 1];
    const int k0 = kt * 64;

    if (k0 <= qw + 31) {                 // wave has unmasked work (wave-uniform)
      f32x4 sacc[4][2];
#pragma unroll
      for (int m = 0; m < 4; ++m)
#pragma unroll
        for (int nq = 0; nq < 2; ++nq) sacc[m][nq] = z4;
#pragma unroll
      for (int kb = 0; kb < 3; ++kb)
#pragma unroll
        for (int m = 0; m < 4; ++m) {
          const bf16x8 kfrag = *reinterpret_cast<const bf16x8*>(kc + ((m * 3 + kb) * 64 + lane) * 8);
#pragma unroll
          for (int nq = 0; nq < 2; ++nq)
            sacc[m][nq] = __builtin_amdgcn_mfma_f32_16x16x32_bf16(kfrag, qf[nq][kb], sacc[m][nq], 0, 0, 0);
        }
      if (k0 + 63 > qw) {
#pragma unroll
        for (int m = 0; m < 4; ++m) {
          const int kpos = k0 + m * 16 + fq * 4;
#pragma unroll
          for (int nq = 0; nq < 2; ++nq) {
            const int qpos = qw + nq * 16 + fr;
#pragma unroll
            for (int j = 0; j < 4; ++j)
              if (kpos + j > qpos) sacc[m][nq][j] = -1e30f;
          }
        }
      }
      float al[2];
#pragma unroll
      for (int nq = 0; nq < 2; ++nq) {
        float mx = sacc[0][nq][0];
#pragma unroll
        for (int m = 0; m < 4; ++m)
#pragma unroll
          for (int j = 0; j < 4; ++j) mx = fmaxf(mx, sacc[m][nq][j]);
        mx = fmaxf(mx, __shfl_xor(mx, 16));
        mx = fmaxf(mx, __shfl_xor(mx, 32));
        const float mn = fmaxf(mrow[nq], mx);
        al[nq] = exp2f_fast(mrow[nq] - mn);
        mrow[nq] = mn;
        float s = 0.f;
#pragma unroll
        for (int m = 0; m < 4; ++m) {
          f32x4 p;
#pragma unroll
          for (int j = 0; j < 4; ++j) p[j] = exp2f_fast(sacc[m][nq][j] - mn);
          sacc[m][nq] = p;
          s += (p[0] + p[1]) + (p[2] + p[3]);
        }
        s += __shfl_xor(s, 16);
        s += __shfl_xor(s, 32);
        ssum[nq] = ssum[nq] * al[nq] + s;
      }
      float alb[2][4];
#pragma unroll
      for (int mq = 0; mq < 2; ++mq)
#pragma unroll
        for (int j = 0; j < 4; ++j) alb[mq][j] = __shfl(al[mq], fq * 4 + j);
#pragma unroll
      for (int mq = 0; mq < 2; ++mq)
#pragma unroll
        for (int n2 = 0; n2 < 6; ++n2) {
          f32x4 t = oacc[mq][n2];
          t[0] *= alb[mq][0]; t[1] *= alb[mq][1]; t[2] *= alb[mq][2]; t[3] *= alb[mq][3];
          oacc[mq][n2] = t;
        }
      union PB { u32 u[4]; bf16x8 v; };
      PB pa[2][2];
#pragma unroll
      for (int c = 0; c < 2; ++c)
#pragma unroll
        for (int mq = 0; mq < 2; ++mq) {
          pa[c][mq].u[0] = cvtpk(sacc[2 * c][mq][0], sacc[2 * c][mq][1]);
          pa[c][mq].u[1] = cvtpk(sacc[2 * c][mq][2], sacc[2 * c][mq][3]);
          pa[c][mq].u[2] = cvtpk(sacc[2 * c + 1][mq][0], sacc[2 * c + 1][mq][1]);
          pa[c][mq].u[3] = cvtpk(sacc[2 * c + 1][mq][2], sacc[2 * c + 1][mq][3]);
        }
#pragma unroll
      for (int c = 0; c < 2; ++c)
#pragma unroll
        for (int n2 = 0; n2 < 6; ++n2) {
          const bf16x8 vfrag = *reinterpret_cast<const bf16x8*>(vc + ((n2 * 2 + c) * 64 + lane) * 8);
#pragma unroll
          for (int mq = 0; mq < 2; ++mq)
            oacc[mq][n2] = __builtin_amdgcn_mfma_f32_16x16x32_bf16(pa[c][mq].v, vfrag, oacc[mq][n2], 0, 0, 0);
        }
    }
  }
#undef STAGE

  float inv[2][4];
#pragma unroll
  for (int mq = 0; mq < 2; ++mq)
#pragma unroll
    for (int j = 0; j < 4; ++j)
      inv[mq][j] = __builtin_amdgcn_rcpf(__shfl(ssum[mq], fq * 4 + j));
#pragma unroll
  for (int mq = 0; mq < 2; ++mq)
#pragma unroll
    for (int n2 = 0; n2 < 6; ++n2)
#pragma unroll
      for (int j = 0; j < 4; ++j) {
        const size_t off =
            (size_t)(b * 2048 + qw + mq * 16 + fq * 4 + j) * 1536 + h * 96 + n2 * 16 + fr;
        y[off] = f2bf(oacc[mq][n2][j] * inv[mq][j]);
      }
}

// ---------------------------------------------------------------- launch
extern "C" void kernel_launch(void* const* d_in, const int* in_sizes, int n_in,
                              void* d_out, int out_size, void* d_ws, size_t ws_size,
                              hipStream_t stream) {
  (void)in_sizes; (void)n_in; (void)out_size; (void)ws_size;
  const float* x     = (const float*)d_in[0];
  const float* w_qkv = (const float*)d_in[1];
  const float* w_o   = (const float*)d_in[2];
  const float* Rs    = (const float*)d_in[3];
  float* out = (float*)d_out;

  // ws layout (u16 elems). Kf/Vf alias xb/wqkvb (dead after gemm1). Total 81.8 MB.
  u16* xb    = (u16*)d_ws;            // 6291456
  u16* wqkvb = xb + 6291456;          // 7077888
  u16* wob   = xb + 13369344;         // 2359296
  u16* qkvb  = xb + 15728640;         // 18874368
  u16* yb    = xb + 34603008;         // 6291456
  u16* Kf    = xb;                    // 6291456 (32 bh x 32 kt x 6144)
  u16* Vf    = xb + 6291456;          // 6291456

  cvt_bf16<<<1572864 / 256, 256, 0, stream>>>(x, xb, 1572864);
  cvt_bf16<<<1769472 / 256, 256, 0, stream>>>(w_qkv, wqkvb, 1769472);
  cvt_bf16<<<589824 / 256, 256, 0, stream>>>(w_o, wob, 589824);

  gemm_bal<1><<<dim3(32, 24), 512, 0, stream>>>(xb, wqkvb, (void*)qkvb, 4096, 4608, 1536);
  rope_kernel<<<8192, 256, 0, stream>>>(qkvb, Rs);
  kvprep<<<dim3(32, 32), 256, 0, stream>>>(qkvb, Kf, Vf);
  attn_fwd<<<dim3(32, 16), 256, 0, stream>>>(qkvb, Kf, Vf, yb);
  gemm_bal<0><<<dim3(32, 8), 512, 0, stream>>>(yb, wob, (void*)out, 4096, 1536, 1536);
}

// Round 7
// 272.743 us; speedup vs baseline: 1.2121x; 1.0828x over previous
//
#include <hip/hip_runtime.h>
#include <stdint.h>

// B=2, T=2048, D_MODEL=1536, H=16, hd=96, n_trip=32. qkv row = 4608, rows = 4096.

typedef unsigned short u16;
typedef unsigned int u32;
typedef __attribute__((ext_vector_type(8))) __bf16 bf16x8;   // MFMA A/B frag
typedef __attribute__((ext_vector_type(4))) float f32x4;     // MFMA C/D frag

#define DEV static __device__ __forceinline__

DEV u16 f2bf(float f) {
  u32 u = __float_as_uint(f);
  return (u16)((u + 0x7fffu + ((u >> 16) & 1u)) >> 16);  // RNE
}
DEV float bf2f(u16 h) { return __uint_as_float(((u32)h) << 16); }
DEV u32 cvtpk(float lo, float hi) {  // packed f32->bf16 pair (lo->bits[15:0])
  u32 r;
  asm("v_cvt_pk_bf16_f32 %0, %1, %2" : "=v"(r) : "v"(lo), "v"(hi));
  return r;
}
DEV float exp2f_fast(float x) {
  float r;
  asm("v_exp_f32 %0, %1" : "=v"(r) : "v"(x));
  return r;
}
DEV float max3f(float a, float b, float c) { return fmaxf(fmaxf(a, b), c); }

// async global->LDS, 16B/lane. LDS dest = wave-uniform base + lane*16.
DEV void gload16(u16* lds_dst, const u16* gsrc) {
  __builtin_amdgcn_global_load_lds(
      (const __attribute__((address_space(1))) void*)gsrc,
      (__attribute__((address_space(3))) void*)lds_dst, 16, 0, 0);
}

// ---------------------------------------------------------------- cvt f32->bf16 x3
__global__ __launch_bounds__(256) void cvt3(const float* __restrict__ a, u16* __restrict__ ao, int na4,
                                            const float* __restrict__ b, u16* __restrict__ bo, int nb4,
                                            const float* __restrict__ c, u16* __restrict__ co, int nc4) {
  int i = blockIdx.x * 256 + threadIdx.x;
  const float* src;
  u16* dst;
  if (i < na4) { src = a; dst = ao; }
  else if (i < na4 + nb4) { i -= na4; src = b; dst = bo; }
  else if (i < na4 + nb4 + nc4) { i -= na4 + nb4; src = c; dst = co; }
  else return;
  float4 v = reinterpret_cast<const float4*>(src)[i];
  ushort4 o;
  o.x = f2bf(v.x); o.y = f2bf(v.y); o.z = f2bf(v.z); o.w = f2bf(v.w);
  reinterpret_cast<ushort4*>(dst)[i] = o;
}

// ---------------------------------------------------------------- GEMM (128x192)
// Balanced-fill pipelined GEMM: C = A * B^T. BM=128, BN=192, BK=64.
// grid = (M/128, N/192); gemm1: 768 = 3*256 blocks, gemm2: 256 blocks.
// LDS 80 KiB (dbuf) -> 2 blocks/CU. 8 waves as 2M x 4N -> wave tile 64x48.
template <int OUT_BF16>
__global__ __launch_bounds__(512, 4) void gemm_bal(const u16* __restrict__ A,
                                                   const u16* __restrict__ B,
                                                   void* __restrict__ Cv,
                                                   int M, int N, int K) {
  (void)M;
  __shared__ __align__(16) u16 sA[2][128 * 64];   // 16 KiB per buf
  __shared__ __align__(16) u16 sB[2][192 * 64];   // 24 KiB per buf
  const int tid = threadIdx.x;                    // 0..511
  const int lane = tid & 63, w = tid >> 6;
  const int wm = w >> 2, wn = w & 3;              // wave grid 2M x 4N
  const int fr = lane & 15, fq = lane >> 4;
  const int r0 = blockIdx.x * 128, c0 = blockIdx.y * 192;

  const u16* aSrc[2];
  const u16* bSrc[3];
#pragma unroll
  for (int c = 0; c < 2; ++c) {
    const int idx = c * 512 + tid;
    const int row = idx >> 3;
    aSrc[c] = A + (size_t)(r0 + row) * K + ((idx & 7) ^ (row & 7)) * 8;
  }
#pragma unroll
  for (int c = 0; c < 3; ++c) {
    const int idx = c * 512 + tid;
    const int row = idx >> 3;
    bSrc[c] = B + (size_t)(c0 + row) * K + ((idx & 7) ^ (row & 7)) * 8;
  }

  const int sw0 = ((fq) ^ (fr & 7)) * 8;
  const int sw1 = ((4 + fq) ^ (fr & 7)) * 8;
  const int aB = (wm * 64 + fr) * 64;
  const int bB = (wn * 48 + fr) * 64;

  const f32x4 z4 = {0.f, 0.f, 0.f, 0.f};
  f32x4 acc[4][3];
#pragma unroll
  for (int m = 0; m < 4; ++m)
#pragma unroll
    for (int n = 0; n < 3; ++n) acc[m][n] = z4;

  const int NT = K >> 6;

#define SGA(c, buf, ko) gload16(&sA[buf][((c)*512 + w * 64) * 8], aSrc[c] + (ko))
#define SGB(c, buf, ko) gload16(&sB[buf][((c)*512 + w * 64) * 8], bSrc[c] + (ko))

  SGA(0, 0, 0); SGA(1, 0, 0);
  SGB(0, 0, 0); SGB(1, 0, 0); SGB(2, 0, 0);

  for (int u = 0; u < NT; ++u) {
    const int par = u & 1, nxt = par ^ 1;
    const u16* a = sA[par];
    const u16* b = sB[par];
    const bool pf = (u + 1 < NT);
    const size_t ko = (size_t)(u + 1) * 64;

    asm volatile("s_waitcnt vmcnt(3)" ::: "memory");
    __builtin_amdgcn_s_barrier();
    if (pf) { SGA(0, nxt, ko); SGA(1, nxt, ko); }

    if (pf) { asm volatile("s_waitcnt vmcnt(2)" ::: "memory"); }
    else    { asm volatile("s_waitcnt vmcnt(0)" ::: "memory"); }
    __builtin_amdgcn_s_barrier();
    bf16x8 bfr[3][2];
#pragma unroll
    for (int n = 0; n < 3; ++n) {
      bfr[n][0] = *(const bf16x8*)(b + bB + n * 1024 + sw0);
      bfr[n][1] = *(const bf16x8*)(b + bB + n * 1024 + sw1);
    }
    if (pf) { SGB(0, nxt, ko); SGB(1, nxt, ko); SGB(2, nxt, ko); }
    __builtin_amdgcn_s_barrier();
    __builtin_amdgcn_s_setprio(1);
#pragma unroll
    for (int mp = 0; mp < 2; ++mp) {
      bf16x8 afr[2][2];
#pragma unroll
      for (int i = 0; i < 2; ++i) {
        afr[i][0] = *(const bf16x8*)(a + aB + (2 * mp + i) * 1024 + sw0);
        afr[i][1] = *(const bf16x8*)(a + aB + (2 * mp + i) * 1024 + sw1);
      }
#pragma unroll
      for (int i = 0; i < 2; ++i)
#pragma unroll
        for (int n = 0; n < 3; ++n)
#pragma unroll
          for (int ks = 0; ks < 2; ++ks)
            acc[2 * mp + i][n] = __builtin_amdgcn_mfma_f32_16x16x32_bf16(
                afr[i][ks], bfr[n][ks], acc[2 * mp + i][n], 0, 0, 0);
    }
    __builtin_amdgcn_s_setprio(0);
  }
#undef SGA
#undef SGB

#pragma unroll
  for (int m = 0; m < 4; ++m) {
    const int gr = r0 + wm * 64 + m * 16 + fq * 4;
#pragma unroll
    for (int n = 0; n < 3; ++n) {
      const int gc = c0 + wn * 48 + n * 16 + fr;
#pragma unroll
      for (int j = 0; j < 4; ++j) {
        const size_t off = (size_t)(gr + j) * N + gc;
        if (OUT_BF16) ((u16*)Cv)[off] = f2bf(acc[m][n][j]);
        else          ((float*)Cv)[off] = acc[m][n][j];
      }
    }
  }
}

// ---------------------------------------------------------------- 3D RoPE on q,k
// One block per bt: rotates q (offset 0) and k (offset 1536) in place; Rs loaded once.
__global__ __launch_bounds__(256) void rope_kernel(u16* __restrict__ qkv,
                                                   const float* __restrict__ Rs) {
  const int bt = blockIdx.x;         // [0, 4096)
  const int t = bt & 2047;
  const int tid = threadIdx.x;

  __shared__ __align__(16) u16 buf[3072];
  __shared__ __align__(16) float rbuf[288];

  u16* g = qkv + (size_t)bt * 4608;  // q at 0, k at 1536
#pragma unroll
  for (int r = 0; r < 2; ++r) {
    const int idx = r * 256 + tid;
    if (idx < 384)
      *reinterpret_cast<uint4*>(buf + idx * 8) = *reinterpret_cast<const uint4*>(g + idx * 8);
  }
  if (tid < 72)
    *reinterpret_cast<float4*>(rbuf + tid * 4) =
        *reinterpret_cast<const float4*>(Rs + (size_t)t * 288 + tid * 4);
  __syncthreads();

#pragma unroll
  for (int rep = 0; rep < 4; ++rep) {
    const int ft = rep * 256 + tid;          // [0,1024): qk = ft>>9, h=(ft&511)>>5, trip=ft&31
    const int base = (ft >> 9) * 1536 + ((ft & 511) >> 5) * 96 + (ft & 31) * 3;
    const float* R = rbuf + (ft & 31) * 9;
    const float x0 = bf2f(buf[base]), x1 = bf2f(buf[base + 1]), x2 = bf2f(buf[base + 2]);
    const float y0 = R[0] * x0 + R[1] * x1 + R[2] * x2;
    const float y1 = R[3] * x0 + R[4] * x1 + R[5] * x2;
    const float y2 = R[6] * x0 + R[7] * x1 + R[8] * x2;
    buf[base] = f2bf(y0); buf[base + 1] = f2bf(y1); buf[base + 2] = f2bf(y2);
  }
  __syncthreads();
#pragma unroll
  for (int r = 0; r < 2; ++r) {
    const int idx = r * 256 + tid;
    if (idx < 384)
      *reinterpret_cast<uint4*>(g + idx * 8) = *reinterpret_cast<const uint4*>(buf + idx * 8);
  }
}

// ---------------------------------------------------------------- KV fragment prep
__global__ __launch_bounds__(256) void kvprep(const u16* __restrict__ qkv,
                                              u16* __restrict__ Kf,
                                              u16* __restrict__ Vf) {
  const int kt = blockIdx.x, bh = blockIdx.y;
  const int b = bh >> 4, h = bh & 15;
  const int tid = threadIdx.x, lane = tid & 63, w = tid >> 6;
  const float SC = 0.14724574f;  // (1/sqrt(96)) * log2(e)
  __shared__ __align__(16) u16 vlds[64 * 96];

#pragma unroll
  for (int r = 0; r < 3; ++r) {
    const int idx = r * 256 + tid;
    const int kv = idx / 12, c8 = (idx % 12) * 8;
    gload16(vlds + (r * 256 + w * 64) * 8,
            qkv + (size_t)(b * 2048 + kt * 64 + kv) * 4608 + 3072 + h * 96 + c8);
  }

  const size_t obase = ((size_t)bh * 32 + kt) * 6144;
#pragma unroll
  for (int r = 0; r < 3; ++r) {
    const int chunk = r * 256 + tid;
    const int sub = chunk >> 6, l = chunk & 63;
    const int m = sub / 3, kb = sub % 3;
    const int fr = l & 15, fq = l >> 4;
    uint4 v = *reinterpret_cast<const uint4*>(
        qkv + (size_t)(b * 2048 + kt * 64 + m * 16 + fr) * 4608 + 1536 + h * 96 + kb * 32 + fq * 8);
    u16* p = reinterpret_cast<u16*>(&v);
#pragma unroll
    for (int e = 0; e < 8; ++e) p[e] = f2bf(bf2f(p[e]) * SC);
    *reinterpret_cast<uint4*>(Kf + obase + (size_t)chunk * 8) = v;
  }
  __syncthreads();
#pragma unroll
  for (int r = 0; r < 3; ++r) {
    const int chunk = r * 256 + tid;
    const int sub = chunk >> 6, l = chunk & 63;
    const int n2 = sub >> 1, c = sub & 1;
    const int fr = l & 15, fq = l >> 4;
    const int d = n2 * 16 + fr;
    u16 out[8];
#pragma unroll
    for (int e = 0; e < 8; ++e) {
      const int kl = (c * 2 + (e >> 2)) * 16 + fq * 4 + (e & 3);
      out[e] = vlds[kl * 96 + d];
    }
    *reinterpret_cast<uint4*>(Vf + obase + (size_t)chunk * 8) =
        *reinterpret_cast<uint4*>(out);
  }
}

// ---------------------------------------------------------------- flash attention
// Block = 128 Q-rows, 4 waves x 32 rows. Swapped QK^T; ones-column denominator;
// T13 defer-max (THR=8, exp2 domain).
__global__ __launch_bounds__(256, 2) void attn_fwd(const u16* __restrict__ qkvb,
                                                   const u16* __restrict__ Kf,
                                                   const u16* __restrict__ Vf,
                                                   u16* __restrict__ y) {
  const int bh = blockIdx.x;
  const int qt = 15 - (int)blockIdx.y;   // LPT: heavy blocks dispatched first
  const int b = bh >> 4, h = bh & 15;
  const int tid = threadIdx.x, lane = tid & 63, w = tid >> 6;
  const int fr = lane & 15, fq = lane >> 4;
  const int q0 = qt * 128;
  const int qw = q0 + w * 32;            // wave's first q row

  __shared__ __align__(16) u16 kbl[2][6144];
  __shared__ __align__(16) u16 vbl[2][6144];

  bf16x8 qf[2][3];
#pragma unroll
  for (int nq = 0; nq < 2; ++nq)
#pragma unroll
    for (int kb = 0; kb < 3; ++kb)
      qf[nq][kb] = *reinterpret_cast<const bf16x8*>(
          qkvb + (size_t)(b * 2048 + qw + nq * 16 + fr) * 4608 + h * 96 + kb * 32 + fq * 8);

  union OneU { u16 s[8]; bf16x8 v; };
  OneU ou;
#pragma unroll
  for (int e = 0; e < 8; ++e) ou.s[e] = 0x3f80;  // bf16 1.0
  const bf16x8 vones = ou.v;

  const f32x4 z4 = {0.f, 0.f, 0.f, 0.f};
  f32x4 oacc[2][7];                      // [..][6] = ones-column denominator
#pragma unroll
  for (int mq = 0; mq < 2; ++mq)
#pragma unroll
    for (int n2 = 0; n2 < 7; ++n2) oacc[mq][n2] = z4;
  float mrow[2] = {-1e30f, -1e30f};

  const int nt = 2 * qt + 2;
  const size_t tb = (size_t)bh * 32 * 6144;

#define STAGE(buf, kt_)                                                         \
  do {                                                                          \
    const size_t sb = tb + (size_t)(kt_)*6144;                                  \
    _Pragma("unroll") for (int r = 0; r < 3; ++r) {                             \
      gload16(kbl[buf] + (r * 256 + w * 64) * 8, Kf + sb + (r * 256 + w * 64 + lane) * 8); \
      gload16(vbl[buf] + (r * 256 + w * 64) * 8, Vf + sb + (r * 256 + w * 64 + lane) * 8); \
    }                                                                           \
  } while (0)

  STAGE(0, 0);
  for (int kt = 0; kt < nt; ++kt) {
    __syncthreads();                     // stage(kt) landed; compute(kt-1) done
    if (kt + 1 < nt) STAGE((kt + 1) & 1, kt + 1);
    const u16* kc = kbl[kt & 1];
    const u16* vc = vbl[kt & 1];
    const int k0 = kt * 64;

    if (k0 <= qw + 31) {                 // wave has unmasked work (wave-uniform)
      // ---- S^T = K Q (log2 domain; K pre-scaled)
      f32x4 sacc[4][2];
#pragma unroll
      for (int m = 0; m < 4; ++m)
#pragma unroll
        for (int nq = 0; nq < 2; ++nq) sacc[m][nq] = z4;
#pragma unroll
      for (int kb = 0; kb < 3; ++kb)
#pragma unroll
        for (int m = 0; m < 4; ++m) {
          const bf16x8 kfrag = *reinterpret_cast<const bf16x8*>(kc + ((m * 3 + kb) * 64 + lane) * 8);
#pragma unroll
          for (int nq = 0; nq < 2; ++nq)
            sacc[m][nq] = __builtin_amdgcn_mfma_f32_16x16x32_bf16(kfrag, qf[nq][kb], sacc[m][nq], 0, 0, 0);
        }
      if (k0 + 63 > qw) {                // diagonal: mask kpos > qpos
#pragma unroll
        for (int m = 0; m < 4; ++m) {
          const int kpos = k0 + m * 16 + fq * 4;
#pragma unroll
          for (int nq = 0; nq < 2; ++nq) {
            const int qpos = qw + nq * 16 + fr;
#pragma unroll
            for (int j = 0; j < 4; ++j)
              if (kpos + j > qpos) sacc[m][nq][j] = -1e30f;
          }
        }
      }
      // ---- row max via max3 tree + cross-group reduce
      float mx[2];
#pragma unroll
      for (int nq = 0; nq < 2; ++nq) {
        const float t0 = max3f(sacc[0][nq][0], sacc[0][nq][1], sacc[0][nq][2]);
        const float t1 = max3f(sacc[0][nq][3], sacc[1][nq][0], sacc[1][nq][1]);
        const float t2 = max3f(sacc[1][nq][2], sacc[1][nq][3], sacc[2][nq][0]);
        const float t3 = max3f(sacc[2][nq][1], sacc[2][nq][2], sacc[2][nq][3]);
        const float t4 = max3f(sacc[3][nq][0], sacc[3][nq][1], sacc[3][nq][2]);
        float m = max3f(max3f(t0, t1, t2), t3, max3f(t4, sacc[3][nq][3], t0));
        m = fmaxf(m, __shfl_xor(m, 16));
        m = fmaxf(m, __shfl_xor(m, 32));
        mx[nq] = m;
      }
      // ---- T13 defer-max: rescale only when max grew > THR (wave-uniform)
      const bool need = (mx[0] - mrow[0] > 8.0f) || (mx[1] - mrow[1] > 8.0f);
      if (__any(need)) {
        float al[2];
#pragma unroll
        for (int nq = 0; nq < 2; ++nq) {
          const float mn = fmaxf(mrow[nq], mx[nq]);
          al[nq] = exp2f_fast(mrow[nq] - mn);
          mrow[nq] = mn;
        }
        float alb[2][4];
#pragma unroll
        for (int mq = 0; mq < 2; ++mq)
#pragma unroll
          for (int j = 0; j < 4; ++j) alb[mq][j] = __shfl(al[mq], fq * 4 + j);
#pragma unroll
        for (int mq = 0; mq < 2; ++mq)
#pragma unroll
          for (int n2 = 0; n2 < 7; ++n2) {
            f32x4 t = oacc[mq][n2];
            t[0] *= alb[mq][0]; t[1] *= alb[mq][1]; t[2] *= alb[mq][2]; t[3] *= alb[mq][3];
            oacc[mq][n2] = t;
          }
      }
      // ---- P = exp2(S - mrow)
#pragma unroll
      for (int nq = 0; nq < 2; ++nq)
#pragma unroll
        for (int m = 0; m < 4; ++m) {
          f32x4 p;
#pragma unroll
          for (int j = 0; j < 4; ++j) p[j] = exp2f_fast(sacc[m][nq][j] - mrow[nq]);
          sacc[m][nq] = p;
        }
      // ---- pack P from registers (k-permutation matches Vf layout)
      union PB { u32 u[4]; bf16x8 v; };
      PB pa[2][2];
#pragma unroll
      for (int c = 0; c < 2; ++c)
#pragma unroll
        for (int mq = 0; mq < 2; ++mq) {
          pa[c][mq].u[0] = cvtpk(sacc[2 * c][mq][0], sacc[2 * c][mq][1]);
          pa[c][mq].u[1] = cvtpk(sacc[2 * c][mq][2], sacc[2 * c][mq][3]);
          pa[c][mq].u[2] = cvtpk(sacc[2 * c + 1][mq][0], sacc[2 * c + 1][mq][1]);
          pa[c][mq].u[3] = cvtpk(sacc[2 * c + 1][mq][2], sacc[2 * c + 1][mq][3]);
        }
      // ---- O += P V  (n2==6: ones column accumulates the denominator)
#pragma unroll
      for (int c = 0; c < 2; ++c)
#pragma unroll
        for (int n2 = 0; n2 < 7; ++n2) {
          const bf16x8 vfrag = (n2 < 6)
              ? *reinterpret_cast<const bf16x8*>(vc + ((n2 * 2 + c) * 64 + lane) * 8)
              : vones;
#pragma unroll
          for (int mq = 0; mq < 2; ++mq)
            oacc[mq][n2] = __builtin_amdgcn_mfma_f32_16x16x32_bf16(pa[c][mq].v, vfrag, oacc[mq][n2], 0, 0, 0);
        }
    }
  }
#undef STAGE

  // ---- epilogue: denominator lives in oacc[mq][6][j] (lane-local, no shfl)
  float inv[2][4];
#pragma unroll
  for (int mq = 0; mq < 2; ++mq)
#pragma unroll
    for (int j = 0; j < 4; ++j)
      inv[mq][j] = __builtin_amdgcn_rcpf(oacc[mq][6][j]);
#pragma unroll
  for (int mq = 0; mq < 2; ++mq)
#pragma unroll
    for (int n2 = 0; n2 < 6; ++n2)
#pragma unroll
      for (int j = 0; j < 4; ++j) {
        const size_t off =
            (size_t)(b * 2048 + qw + mq * 16 + fq * 4 + j) * 1536 + h * 96 + n2 * 16 + fr;
        y[off] = f2bf(oacc[mq][n2][j] * inv[mq][j]);
      }
}

// ---------------------------------------------------------------- launch
extern "C" void kernel_launch(void* const* d_in, const int* in_sizes, int n_in,
                              void* d_out, int out_size, void* d_ws, size_t ws_size,
                              hipStream_t stream) {
  (void)in_sizes; (void)n_in; (void)out_size; (void)ws_size;
  const float* x     = (const float*)d_in[0];
  const float* w_qkv = (const float*)d_in[1];
  const float* w_o   = (const float*)d_in[2];
  const float* Rs    = (const float*)d_in[3];
  float* out = (float*)d_out;

  // ws layout (u16 elems). Kf/Vf alias xb/wqkvb (dead after gemm1). Total 81.8 MB.
  u16* xb    = (u16*)d_ws;            // 6291456
  u16* wqkvb = xb + 6291456;          // 7077888
  u16* wob   = xb + 13369344;         // 2359296
  u16* qkvb  = xb + 15728640;         // 18874368
  u16* yb    = xb + 34603008;         // 6291456
  u16* Kf    = xb;                    // 6291456 (32 bh x 32 kt x 6144)
  u16* Vf    = xb + 6291456;          // 6291456

  cvt3<<<(1572864 + 1769472 + 589824) / 256, 256, 0, stream>>>(
      x, xb, 1572864, w_qkv, wqkvb, 1769472, w_o, wob, 589824);

  gemm_bal<1><<<dim3(32, 24), 512, 0, stream>>>(xb, wqkvb, (void*)qkvb, 4096, 4608, 1536);
  rope_kernel<<<4096, 256, 0, stream>>>(qkvb, Rs);
  kvprep<<<dim3(32, 32), 256, 0, stream>>>(qkvb, Kf, Vf);
  attn_fwd<<<dim3(32, 16), 256, 0, stream>>>(qkvb, Kf, Vf, yb);
  gemm_bal<0><<<dim3(32, 8), 512, 0, stream>>>(yb, wob, (void*)out, 4096, 1536, 1536);
}